// Round 13
// baseline (56.958 us; speedup 1.0000x reference)
//
#include <hip/hip_runtime.h>
#include <hip/hip_bf16.h>

// SimilarityLayer: out[e,q,w,n,m] = <p[e,w,:,n], q[e,q,:,m]> / (|p||q| + 1e-8)
// E=8 W=5 C=640 N=49 Q=75.
// R13: R9/R12 null (drain vs no-drain identical) => binder is VMEM *throughput*
//      (strided scalars: ~6 part-used lines/inst). Return to measured-fast
//      gemm2 (pure frag-load+MFMA, ~9us) and rebuild prep_b with ZERO strided
//      global access: coalesced float4 in -> fp32 LDS (strided b32 = 2-way
//      free) -> cvt -> coalesced 16B granule store. 2400 B-blocks (e,q,quarter,
//      5 chunks), 3-stage 1-barrier/chunk pipeline, raw lgkm-only barriers.

#define E_CNT 8
#define W_CNT 5
#define C_CNT 640
#define N_CNT 49
#define Q_CNT 75
#define MROWS 245                    // W*N
#define NC32 20                      // K chunks of 32
#define CHF 1568                     // floats per B chunk (32 x 49)
#define AFRAG_CH 16384               // per (e,chunk): 16 row-tiles x 64 lanes x 16B
#define AIMG_E (NC32 * AFRAG_CH)     // 327,680 B per e
#define AIMG_SIZE (E_CNT * AIMG_E)   // 2,621,440
#define PN_OFF AIMG_SIZE
#define PN_BYTES (E_CNT * 10 * MROWS * 4)
#define WS1 ((size_t)(PN_OFF + PN_BYTES))            // tier-1 (A-image only)

#define BIMG_EQ 81920                // per (e,q): 20 chunks x 4096 B
#define BIMG_OFF WS1
#define BIMG_SIZE (600 * BIMG_EQ)    // 49,152,000
#define QN_OFF (BIMG_OFF + BIMG_SIZE)
#define QN_BYTES (600 * 256 * 4)     // per (e,q): 4 quarters x 64 cols
#define WS2 ((size_t)(QN_OFF + QN_BYTES))            // tier-2 (full)

typedef __attribute__((ext_vector_type(8))) short bf16x8;
typedef __attribute__((ext_vector_type(4))) float f32x4;

static __device__ __forceinline__ short f2bf(float f) {
    __hip_bfloat16 h = __float2bfloat16(f);
    return *reinterpret_cast<short*>(&h);
}

// Raw barrier WITHOUT vmcnt drain: LDS visibility only; global loads stay in flight.
#define RAW_BARRIER() asm volatile("s_waitcnt lgkmcnt(0)\n\ts_barrier" ::: "memory")

// ---------------- combined prep: B (blocks 0..2399) + A (2400..2479) ---------
__global__ __launch_bounds__(256, 8)
void prep_combined_kernel(const float* __restrict__ proto,
                          const float* __restrict__ query,
                          unsigned char* __restrict__ aimg,
                          float* __restrict__ pn_part,
                          unsigned char* __restrict__ bimg,
                          float* __restrict__ qn_part)
{
    __shared__ float shm[256];
    __shared__ __align__(16) float fbuf[2][CHF];   // fp32 chunk, double-buffered
    const int b = blockIdx.x;
    const int t = threadIdx.x;

    if (b < 2400) {
        // ---- B role: (e,q) k-quarter = 5 chunks of 32, coalesced LDS transpose
        const int eq = b >> 2, quarter = b & 3;
        const float* __restrict__ src = query + (size_t)eq * (C_CNT * N_CNT)
                                              + (size_t)(quarter * 5) * CHF;
        unsigned char* __restrict__ bout = bimg + (size_t)eq * BIMG_EQ
                                                + (size_t)(quarter * 5) * 4096;
        // this thread's fragment granule: fj = t>>6, lane = t&63
        const int col = ((t >> 6) << 4) | (t & 15);
        const int colc = (col < N_CNT) ? col : (N_CNT - 1);
        const int kk0 = ((t >> 4) & 3) * 8;        // k-group within chunk
        const bool t2 = t < (CHF / 4 - 256);       // 136 threads carry 2nd float4

        if (t < 64) shm[t] = 0.f;

        f32x4 vq0a, vq1a, vq0b, vq1b;
        float ssq = 0.f;

#define PB_GLOADA(c) do {                                                       \
        const float* p_ = src + (size_t)(c) * CHF;                              \
        vq0a = *reinterpret_cast<const f32x4*>(p_ + t * 4);                     \
        if (t2) vq1a = *reinterpret_cast<const f32x4*>(p_ + 1024 + t * 4);      \
    } while (0)
#define PB_GLOADB(c) do {                                                       \
        const float* p_ = src + (size_t)(c) * CHF;                              \
        vq0b = *reinterpret_cast<const f32x4*>(p_ + t * 4);                     \
        if (t2) vq1b = *reinterpret_cast<const f32x4*>(p_ + 1024 + t * 4);      \
    } while (0)
#define PB_FPWA(c) do {                                                         \
        float* d_ = fbuf[(c) & 1];                                              \
        *reinterpret_cast<f32x4*>(d_ + t * 4) = vq0a;                           \
        if (t2) *reinterpret_cast<f32x4*>(d_ + 1024 + t * 4) = vq1a;            \
    } while (0)
#define PB_FPWB(c) do {                                                         \
        float* d_ = fbuf[(c) & 1];                                              \
        *reinterpret_cast<f32x4*>(d_ + t * 4) = vq0b;                           \
        if (t2) *reinterpret_cast<f32x4*>(d_ + 1024 + t * 4) = vq1b;            \
    } while (0)
#define PB_CVTST(c) do {                                                        \
        const float* f_ = fbuf[(c) & 1];                                        \
        bf16x8 pk_; float s8_ = 0.f;                                            \
        _Pragma("unroll")                                                       \
        for (int j_ = 0; j_ < 8; ++j_) {                                        \
            const float v_ = f_[(kk0 + j_) * N_CNT + colc];                     \
            s8_ += v_ * v_; pk_[j_] = f2bf(v_);                                 \
        }                                                                       \
        ssq += s8_;                                                             \
        *reinterpret_cast<bf16x8*>(bout + (size_t)(c) * 4096 + t * 16) = pk_;   \
    } while (0)

        // 3-stage pipeline: GLOAD(c+2) | CVTST(c) | FPW(c+1) | BARRIER
        PB_GLOADA(0); PB_FPWA(0);
        PB_GLOADB(1);
        RAW_BARRIER();
        /*c=0*/ PB_GLOADA(2); PB_CVTST(0); PB_FPWB(1); RAW_BARRIER();
        /*c=1*/ PB_GLOADB(3); PB_CVTST(1); PB_FPWA(2); RAW_BARRIER();
        /*c=2*/ PB_GLOADA(4); PB_CVTST(2); PB_FPWB(3); RAW_BARRIER();
        /*c=3*/               PB_CVTST(3); PB_FPWA(4); RAW_BARRIER();
        /*c=4*/               PB_CVTST(4);
#undef PB_GLOADA
#undef PB_GLOADB
#undef PB_FPWA
#undef PB_FPWB
#undef PB_CVTST

        atomicAdd(&shm[col], ssq);         // 4 lk-threads per col; cols>=49 garbage (masked later)
        __syncthreads();
        if (t < 64) qn_part[(size_t)eq * 256 + quarter * 64 + t] = shm[t];
    } else {
        // ---- A role: proto -> fragment-ordered bf16 A image + partial norms --
        const int b2 = b - 2400;           // 80 = e*10 + c64
        const int e = b2 / 10, c64 = b2 % 10;
        const float* pbase = proto + (size_t)e * (W_CNT * C_CNT * N_CNT);
        unsigned char* ebase = aimg + (size_t)e * AIMG_E;
        if (t < MROWS) shm[t] = 0.f;
        __syncthreads();

        #pragma unroll
        for (int i = 0; i < 8; ++i) {
            const int s = t + i * 256;     // slot = kb*245 + nw, kb in [0,8)
            int nw, kb;
            bf16x8 pk;
            if (s < 8 * MROWS) {
                kb = s / MROWS;
                nw = s - kb * MROWS;
                const int w = nw / N_CNT, n = nw - w * N_CNT;
                const float* g = pbase + ((size_t)(w * C_CNT + c64 * 64 + kb * 8)) * N_CNT + n;
                float ss = 0.f;
                #pragma unroll
                for (int j = 0; j < 8; ++j) {
                    const float f = g[(size_t)j * N_CNT];
                    ss += f * f;
                    pk[j] = f2bf(f);
                }
                atomicAdd(&shm[nw], ss);
            } else {
                const int x = s - 8 * MROWS;   // zero-pad rows 245..255
                nw = MROWS + (x >> 3);
                kb = x & 7;
                pk = (bf16x8){0, 0, 0, 0, 0, 0, 0, 0};
            }
            const int c32 = c64 * 2 + (kb >> 2);
            const int ln2 = ((kb & 3) << 4) | (nw & 15);
            *reinterpret_cast<bf16x8*>(
                ebase + (size_t)c32 * AFRAG_CH + (size_t)((nw >> 4) * 64 + ln2) * 16) = pk;
        }
        __syncthreads();
        if (t < MROWS) pn_part[(size_t)(e * 10 + c64) * MROWS + t] = shm[t];
    }
}

// ---------------- gemm2: pure frag-load + MFMA (measured fast) ---------------
__global__ __launch_bounds__(512, 4)
void gemm2_kernel(const unsigned char* __restrict__ aimg,
                  const unsigned char* __restrict__ bimg,
                  const float* __restrict__ pn_part,
                  const float* __restrict__ qn_part,
                  float* __restrict__ out)
{
    __shared__ float pnl[256];
    const int b = blockIdx.x;            // 600
    const int e = b & 7;                 // same e -> same XCD -> A image L2-hot
    const int q = b >> 3;
    const int eq = e * Q_CNT + q;
    const int t = threadIdx.x, wv = t >> 6, ln = t & 63;
    const int lrow = ln & 15, lk = ln >> 4;

    const unsigned char* __restrict__ abase =
        aimg + (size_t)e * AIMG_E + (size_t)((wv * 2) * 64 + ln) * 16;
    const unsigned char* __restrict__ bbase =
        bimg + (size_t)eq * BIMG_EQ + (size_t)ln * 16;

    if (t < MROWS) {
        float s = 0.f;
        #pragma unroll
        for (int cc = 0; cc < 10; ++cc)
            s += pn_part[(size_t)(e * 10 + cc) * MROWS + t];
        pnl[t] = sqrtf(s);
    }
    __syncthreads();

    bf16x8 Af[3][2], Bf[3][4];
    f32x4 acc[2][4];
    #pragma unroll
    for (int i = 0; i < 2; ++i)
        #pragma unroll
        for (int j = 0; j < 4; ++j) acc[i][j] = (f32x4){0.f, 0.f, 0.f, 0.f};

#define LOADA(c, s_) do {                                                       \
    _Pragma("unroll")                                                           \
    for (int fi_ = 0; fi_ < 2; ++fi_)                                           \
        Af[s_][fi_] = *reinterpret_cast<const bf16x8*>(                         \
            abase + (size_t)(c) * AFRAG_CH + fi_ * 1024);                       \
} while (0)

#define LOADB(c, s_) do {                                                       \
    _Pragma("unroll")                                                           \
    for (int fj_ = 0; fj_ < 4; ++fj_)                                           \
        Bf[s_][fj_] = *reinterpret_cast<const bf16x8*>(                         \
            bbase + (size_t)(c) * 4096 + fj_ * 1024);                           \
} while (0)

    LOADA(0, 0); LOADB(0, 0);
    LOADA(1, 1); LOADB(1, 1);

    #pragma unroll
    for (int cc = 0; cc < NC32; ++cc) {
        if (cc + 2 < NC32) {             // 2-ahead into buffer (cc+2)%3
            LOADA(cc + 2, (cc + 2) % 3);
            LOADB(cc + 2, (cc + 2) % 3);
        }
        const int s = cc % 3;            // compile-time (fully unrolled)
        #pragma unroll
        for (int fi = 0; fi < 2; ++fi)
            #pragma unroll
            for (int fj = 0; fj < 4; ++fj)
                acc[fi][fj] = __builtin_amdgcn_mfma_f32_16x16x32_bf16(
                    Af[s][fi], Bf[s][fj], acc[fi][fj], 0, 0, 0);
    }

    // ---- epilogue ----
    const float* __restrict__ qnp = qn_part + (size_t)eq * 256;
    float nq4[4];
    #pragma unroll
    for (int fj = 0; fj < 4; ++fj) {
        const int m = fj * 16 + lrow;
        nq4[fj] = sqrtf(qnp[m] + qnp[64 + m] + qnp[128 + m] + qnp[192 + m]);
    }

    float* __restrict__ osl = out + (size_t)eq * (W_CNT * N_CNT * N_CNT);
    #pragma unroll
    for (int fi = 0; fi < 2; ++fi) {
        #pragma unroll
        for (int rr = 0; rr < 4; ++rr) {
            const int nw = (wv * 2 + fi) * 16 + lk * 4 + rr;  // D row
            if (nw < MROWS) {
                const float np_ = pnl[nw];
                #pragma unroll
                for (int fj = 0; fj < 4; ++fj) {
                    const int m = fj * 16 + lrow;             // D col
                    if (m < N_CNT) {
                        const float den = np_ * nq4[fj] + 1e-8f;
                        osl[nw * N_CNT + m] = acc[fi][fj][rr] * __builtin_amdgcn_rcpf(den);
                    }
                }
            }
        }
    }
#undef LOADA
#undef LOADB
}

// ---------------- tier-1: prep_a standalone + gemm_t1 (R6 path) --------------
__global__ __launch_bounds__(256, 4)
void prep_a_kernel(const float* __restrict__ proto,
                   unsigned char* __restrict__ aimg,
                   float* __restrict__ pn_part)
{
    __shared__ float pns[MROWS];
    const int b = blockIdx.x;
    const int e = b / 10, c64 = b % 10;
    const float* pbase = proto + (size_t)e * (W_CNT * C_CNT * N_CNT);
    unsigned char* ebase = aimg + (size_t)e * AIMG_E;
    const int t = threadIdx.x;
    if (t < MROWS) pns[t] = 0.f;
    __syncthreads();

    #pragma unroll
    for (int i = 0; i < 8; ++i) {
        const int s = t + i * 256;
        int nw, kb;
        bf16x8 pk;
        if (s < 8 * MROWS) {
            kb = s / MROWS;
            nw = s - kb * MROWS;
            const int w = nw / N_CNT, n = nw - w * N_CNT;
            const float* g = pbase + ((size_t)(w * C_CNT + c64 * 64 + kb * 8)) * N_CNT + n;
            float ss = 0.f;
            #pragma unroll
            for (int j = 0; j < 8; ++j) {
                const float f = g[(size_t)j * N_CNT];
                ss += f * f;
                pk[j] = f2bf(f);
            }
            atomicAdd(&pns[nw], ss);
        } else {
            const int x = s - 8 * MROWS;
            nw = MROWS + (x >> 3);
            kb = x & 7;
            pk = (bf16x8){0, 0, 0, 0, 0, 0, 0, 0};
        }
        const int c32 = c64 * 2 + (kb >> 2);
        const int ln2 = ((kb & 3) << 4) | (nw & 15);
        *reinterpret_cast<bf16x8*>(
            ebase + (size_t)c32 * AFRAG_CH + (size_t)((nw >> 4) * 64 + ln2) * 16) = pk;
    }
    __syncthreads();
    if (t < MROWS) pn_part[(size_t)(e * 10 + c64) * MROWS + t] = pns[t];
}

__global__ __launch_bounds__(256, 2)
void gemm_t1_kernel(const float* __restrict__ query,
                    const unsigned char* __restrict__ aimg,
                    const float* __restrict__ pn_part,
                    float* __restrict__ out)
{
    __shared__ float pnl[256];
    const int b = blockIdx.x;
    const int e = b & 7;
    const int q = b >> 3;
    const int t = threadIdx.x;
    const int wv = t >> 6, ln = t & 63;
    const int lrow = ln & 15, lk = ln >> 4;

    const float* __restrict__ qsl = query + (size_t)(e * Q_CNT + q) * (C_CNT * N_CNT);
    const unsigned char* __restrict__ afrag =
        aimg + (size_t)e * AIMG_E + (size_t)((wv * 4) * 64 + ln) * 16;

    int colv[4];
    #pragma unroll
    for (int fj = 0; fj < 4; ++fj) {
        const int c_ = fj * 16 + lrow;
        colv[fj] = (c_ < N_CNT) ? c_ : (N_CNT - 1);
    }
    const int kbase = lk * 8;

    bf16x8 afA[4], afB[4];
    float vbA[4][8], vbB[4][8];
    float ssq[4] = {0.f, 0.f, 0.f, 0.f};
    f32x4 acc[4][4];
    #pragma unroll
    for (int i = 0; i < 4; ++i)
        #pragma unroll
        for (int j = 0; j < 4; ++j) acc[i][j] = (f32x4){0.f, 0.f, 0.f, 0.f};

#define T1_LOADA(c, dst) do {                                                   \
    const unsigned char* ap_ = afrag + (size_t)(c) * AFRAG_CH;                  \
    _Pragma("unroll")                                                           \
    for (int fi_ = 0; fi_ < 4; ++fi_)                                           \
        dst[fi_] = *reinterpret_cast<const bf16x8*>(ap_ + fi_ * 1024);          \
} while (0)

#define T1_LOADB(c, dst) do {                                                   \
    _Pragma("unroll")                                                           \
    for (int fj_ = 0; fj_ < 4; ++fj_) {                                         \
        _Pragma("unroll")                                                       \
        for (int j_ = 0; j_ < 8; ++j_)                                          \
            dst[fj_][j_] = qsl[((c) * 32 + kbase + j_) * N_CNT + colv[fj_]];    \
    }                                                                           \
} while (0)

#define T1_CONVB(src, bfr) do {                                                 \
    _Pragma("unroll")                                                           \
    for (int fj_ = 0; fj_ < 4; ++fj_) {                                         \
        float s8_ = 0.f;                                                        \
        _Pragma("unroll")                                                       \
        for (int j_ = 0; j_ < 8; ++j_) {                                        \
            const float f_ = src[fj_][j_];                                      \
            s8_ += f_ * f_;                                                     \
            bfr[fj_][j_] = f2bf(f_);                                            \
        }                                                                       \
        ssq[fj_] += s8_;                                                        \
    }                                                                           \
} while (0)

#define T1_DOMFMA(af, bfr) do {                                                 \
    _Pragma("unroll")                                                           \
    for (int fi_ = 0; fi_ < 4; ++fi_)                                           \
        _Pragma("unroll")                                                       \
        for (int fj_ = 0; fj_ < 4; ++fj_)                                       \
            acc[fi_][fj_] = __builtin_amdgcn_mfma_f32_16x16x32_bf16(            \
                af[fi_], bfr[fj_], acc[fi_][fj_], 0, 0, 0);                     \
} while (0)

    T1_LOADA(0, afA);
    T1_LOADB(0, vbA);

    for (int cc = 0; cc < NC32; cc += 2) {
        {
            bf16x8 bfr[4];
            T1_CONVB(vbA, bfr);
            T1_LOADA(cc + 1, afB);
            T1_LOADB(cc + 1, vbB);
            T1_DOMFMA(afA, bfr);
        }
        {
            bf16x8 bfr[4];
            T1_CONVB(vbB, bfr);
            if (cc + 2 < NC32) {
                T1_LOADA(cc + 2, afA);
                T1_LOADB(cc + 2, vbA);
            }
            T1_DOMFMA(afB, bfr);
        }
    }

    if (t < MROWS) {
        float s = 0.f;
        #pragma unroll
        for (int cc = 0; cc < 10; ++cc)
            s += pn_part[(size_t)(e * 10 + cc) * MROWS + t];
        pnl[t] = sqrtf(s);
    }
    __syncthreads();

    float nq4[4];
    #pragma unroll
    for (int fj = 0; fj < 4; ++fj) {
        float s = ssq[fj];
        s += __shfl_xor(s, 16);
        s += __shfl_xor(s, 32);
        nq4[fj] = sqrtf(s);
    }

    float* __restrict__ osl = out + (size_t)(e * Q_CNT + q) * (W_CNT * N_CNT * N_CNT);
    #pragma unroll
    for (int fi = 0; fi < 4; ++fi) {
        #pragma unroll
        for (int rr = 0; rr < 4; ++rr) {
            const int nw = wv * 64 + fi * 16 + lk * 4 + rr;
            if (nw < MROWS) {
                const float np_ = pnl[nw];
                #pragma unroll
                for (int fj = 0; fj < 4; ++fj) {
                    const int m = fj * 16 + lrow;
                    if (m < N_CNT) {
                        const float den = np_ * nq4[fj] + 1e-8f;
                        osl[nw * N_CNT + m] = acc[fi][fj][rr] * __builtin_amdgcn_rcpf(den);
                    }
                }
            }
        }
    }
#undef T1_LOADA
#undef T1_LOADB
#undef T1_CONVB
#undef T1_DOMFMA
}

// ---------------- tier-0 fallback (R2 kernel, no ws) -------------------------
struct SMemFB {
    unsigned char A[256 * 128];
    unsigned char B[64 * 128];
    float ns[320];
};

__global__ __launch_bounds__(512, 4)
void sim_fallback_kernel(const float* __restrict__ proto,
                         const float* __restrict__ query,
                         float* __restrict__ out)
{
    __shared__ SMemFB smf;
    const int t = threadIdx.x;
    const int e = blockIdx.x / Q_CNT;
    const int q = blockIdx.x - e * Q_CNT;
    const float* pbase = proto + (size_t)e * (W_CNT * C_CNT * N_CNT);
    const float* qbase = query + ((size_t)e * Q_CNT + q) * (C_CNT * N_CNT);
    unsigned char* lds = (unsigned char*)&smf;
    if (t < 320) smf.ns[t] = 0.f;
    if (t < 208) {
        if (t < 88) *reinterpret_cast<f32x4*>(smf.A + 245 * 128 + t * 16) = (f32x4){0.f,0.f,0.f,0.f};
        else        *reinterpret_cast<f32x4*>(smf.B + 49 * 128 + (t - 88) * 16) = (f32x4){0.f,0.f,0.f,0.f};
    }
    const int nslot5 = (t < 304);
    const float* gp[5];
    int offidx[5];
    #pragma unroll
    for (int i = 0; i < 5; ++i) {
        gp[i] = pbase; offidx[i] = 0;
        if (i < 4 || nslot5) {
            const int s = t + i * 512;
            if (s < 1960) {
                const int kb = s / 245, nw = s - kb * 245;
                const int w = nw / 49, n = nw - w * 49;
                gp[i] = pbase + ((size_t)w * C_CNT + kb * 8) * N_CNT + n;
                offidx[i] = (nw * 128 + ((kb ^ (nw & 7)) << 4)) | (nw << 16);
            } else {
                const int s2 = s - 1960;
                const int kb = s2 / 49, mq = s2 - kb * 49;
                gp[i] = qbase + (size_t)(kb * 8) * N_CNT + mq;
                offidx[i] = (32768 + mq * 128 + ((kb ^ (mq & 7)) << 4)) | ((256 + mq) << 16);
            }
        }
    }
    float v[5][8];
    float ss[5] = {0.f,0.f,0.f,0.f,0.f};
    #pragma unroll
    for (int i = 0; i < 4; ++i)
        #pragma unroll
        for (int j = 0; j < 8; ++j) v[i][j] = gp[i][(size_t)j * N_CNT];
    if (nslot5)
        #pragma unroll
        for (int j = 0; j < 8; ++j) v[4][j] = gp[4][(size_t)j * N_CNT];
    f32x4 acc[2][4];
    #pragma unroll
    for (int i = 0; i < 2; ++i)
        #pragma unroll
        for (int j = 0; j < 4; ++j) acc[i][j] = (f32x4){0.f,0.f,0.f,0.f};
    const int wv = t >> 6, ln = t & 63, lrow = ln & 15, lk = ln >> 4;
    for (int kc = 0; kc < 10; ++kc) {
        #pragma unroll
        for (int i = 0; i < 5; ++i) {
            if (i < 4 || nslot5) {
                bf16x8 pk; float s8 = 0.f;
                #pragma unroll
                for (int j = 0; j < 8; ++j) { const float f = v[i][j]; s8 += f*f; pk[j] = f2bf(f); }
                ss[i] += s8;
                *reinterpret_cast<bf16x8*>(lds + (offidx[i] & 0xFFFF)) = pk;
            }
        }
        __syncthreads();
        if (kc < 9) {
            #pragma unroll
            for (int i = 0; i < 4; ++i) {
                gp[i] += 64 * N_CNT;
                #pragma unroll
                for (int j = 0; j < 8; ++j) v[i][j] = gp[i][(size_t)j * N_CNT];
            }
            if (nslot5) {
                gp[4] += 64 * N_CNT;
                #pragma unroll
                for (int j = 0; j < 8; ++j) v[4][j] = gp[4][(size_t)j * N_CNT];
            }
        }
        #pragma unroll
        for (int ks = 0; ks < 2; ++ks) {
            bf16x8 af[2], bfr[4];
            #pragma unroll
            for (int i = 0; i < 2; ++i) {
                const int row = (wv * 2 + i) * 16 + lrow;
                const int gr = (ks * 4 + lk) ^ (row & 7);
                af[i] = *reinterpret_cast<const bf16x8*>(lds + row * 128 + gr * 16);
            }
            #pragma unroll
            for (int j = 0; j < 4; ++j) {
                const int mq = j * 16 + lrow;
                const int gr = (ks * 4 + lk) ^ (mq & 7);
                bfr[j] = *reinterpret_cast<const bf16x8*>(lds + 32768 + mq * 128 + gr * 16);
            }
            #pragma unroll
            for (int i = 0; i < 2; ++i)
                #pragma unroll
                for (int j = 0; j < 4; ++j)
                    acc[i][j] = __builtin_amdgcn_mfma_f32_16x16x32_bf16(af[i], bfr[j], acc[i][j], 0, 0, 0);
        }
        __syncthreads();
    }
    #pragma unroll
    for (int i = 0; i < 5; ++i)
        if (i < 4 || nslot5) atomicAdd(&smf.ns[offidx[i] >> 16], ss[i]);
    __syncthreads();
    float nq[4];
    #pragma unroll
    for (int j = 0; j < 4; ++j) {
        const int mq = j * 16 + lrow;
        nq[j] = (mq < N_CNT) ? sqrtf(smf.ns[256 + mq]) : 1.f;
    }
    float* obase = out + (size_t)(e * Q_CNT + q) * (W_CNT * N_CNT * N_CNT);
    #pragma unroll
    for (int i = 0; i < 2; ++i) {
        #pragma unroll
        for (int rr = 0; rr < 4; ++rr) {
            const int nw = (wv * 2 + i) * 16 + lk * 4 + rr;
            if (nw < W_CNT * N_CNT) {
                const int w = nw / 49, n = nw - w * 49;
                const float np_ = sqrtf(smf.ns[nw]);
                float* orow = obase + ((size_t)w * N_CNT + n) * N_CNT;
                #pragma unroll
                for (int j = 0; j < 4; ++j) {
                    const int mq = j * 16 + lrow;
                    if (mq < N_CNT) orow[mq] = acc[i][j][rr] / (np_ * nq[j] + 1e-8f);
                }
            }
        }
    }
}

extern "C" void kernel_launch(void* const* d_in, const int* in_sizes, int n_in,
                              void* d_out, int out_size, void* d_ws, size_t ws_size,
                              hipStream_t stream)
{
    const float* proto = (const float*)d_in[0];
    const float* query = (const float*)d_in[1];
    float* out = (float*)d_out;

    if (ws_size < WS1) {
        hipLaunchKernelGGL(sim_fallback_kernel, dim3(E_CNT * Q_CNT), dim3(512), 0, stream,
                           proto, query, out);
        return;
    }

    unsigned char* aimg = (unsigned char*)d_ws;
    float* pn_part = (float*)((unsigned char*)d_ws + PN_OFF);

    if (ws_size >= WS2) {
        unsigned char* bimg = (unsigned char*)d_ws + BIMG_OFF;
        float* qn_part = (float*)((unsigned char*)d_ws + QN_OFF);
        hipLaunchKernelGGL(prep_combined_kernel, dim3(2480), dim3(256), 0, stream,
                           proto, query, aimg, pn_part, bimg, qn_part);
        hipLaunchKernelGGL(gemm2_kernel, dim3(E_CNT * Q_CNT), dim3(512), 0, stream,
                           aimg, bimg, pn_part, qn_part, out);
    } else {
        hipLaunchKernelGGL(prep_a_kernel, dim3(E_CNT * 10), dim3(256), 0, stream,
                           proto, aimg, pn_part);
        hipLaunchKernelGGL(gemm_t1_kernel, dim3(E_CNT * Q_CNT), dim3(256), 0, stream,
                           query, aimg, pn_part, out);
    }
}